// Round 1
// baseline (868.039 us; speedup 1.0000x reference)
//
#include <hip/hip_runtime.h>
#include <cstdint>
#include <cstddef>

#define B_   8
#define N_   2048
#define D_   1024
#define DK_  256
#define M_   (B_ * N_)   // 16384
#define TOPK 32

// --------------------------------------------------------------------------
// Kernel 1: fused Q/K projection GEMM with f64 accumulation.
// C[m][c], c in [0,512): c<256 -> Q (Wq,bq), else K (Wk,bk).
// A = X (M x 1024, f32 row-major). Tiles 64x64, BK=16, 4x4 per thread.
// --------------------------------------------------------------------------
__global__ __launch_bounds__(256) void proj_kernel(
    const float* __restrict__ X, const float* __restrict__ Wq,
    const float* __restrict__ bq, const float* __restrict__ Wk,
    const float* __restrict__ bk, double* __restrict__ Qd,
    double* __restrict__ Kd)
{
  __shared__ float As[16][68];   // [k][m], padded
  __shared__ float Bs[16][68];   // [k][j], padded
  const int tid = threadIdx.x;
  const int tx = tid & 15, ty = tid >> 4;
  const int m0 = blockIdx.y * 64;
  const int j0 = blockIdx.x * 64;          // 0..448
  const bool isQ = (j0 < 256);
  const float* Wp = isQ ? Wq : Wk;
  const float* bp = isQ ? bq : bk;
  const int jw = isQ ? j0 : (j0 - 256);    // column offset inside the 256-wide W

  double acc[4][4];
#pragma unroll
  for (int i = 0; i < 4; i++)
#pragma unroll
    for (int j = 0; j < 4; j++) acc[i][j] = 0.0;

  for (int k0 = 0; k0 < D_; k0 += 16) {
    // A tile: 64 rows x 16 k, stored transposed As[k][m]
    {
      const int mt = tid >> 4;   // 0..15
      const int kt = tid & 15;   // 0..15
#pragma unroll
      for (int p = 0; p < 4; p++) {
        const int m = mt + 16 * p;
        As[kt][m] = X[(size_t)(m0 + m) * D_ + k0 + kt];
      }
    }
    // B tile: 16 k x 64 j
    {
      const int kt = tid >> 6;   // 0..3
      const int jt = tid & 63;   // 0..63
#pragma unroll
      for (int p = 0; p < 4; p++) {
        const int k = kt + 4 * p;
        Bs[k][jt] = Wp[(size_t)(k0 + k) * DK_ + jw + jt];
      }
    }
    __syncthreads();
#pragma unroll
    for (int kk = 0; kk < 16; kk++) {
      double a[4], b[4];
#pragma unroll
      for (int i = 0; i < 4; i++) a[i] = (double)As[kk][ty * 4 + i];
#pragma unroll
      for (int j = 0; j < 4; j++) b[j] = (double)Bs[kk][tx * 4 + j];
#pragma unroll
      for (int i = 0; i < 4; i++)
#pragma unroll
        for (int j = 0; j < 4; j++)
          acc[i][j] = fma(a[i], b[j], acc[i][j]);
    }
    __syncthreads();
  }

#pragma unroll
  for (int i = 0; i < 4; i++) {
    const int m = m0 + ty * 4 + i;
#pragma unroll
    for (int j = 0; j < 4; j++) {
      const int c = jw + tx * 4 + j;         // 0..255
      const double v = acc[i][j] + (double)bp[c];
      if (isQ) Qd[(size_t)m * DK_ + c] = v;
      else     Kd[(size_t)m * DK_ + c] = v;
    }
  }
}

// --------------------------------------------------------------------------
// Kernel 2: scores GEMM in f32 (candidate generation only).
// out[b][q][m] = (Qd[bq] . Kd[bm]) / 16, rounded through f32 inputs.
// --------------------------------------------------------------------------
__global__ __launch_bounds__(256) void score_kernel(
    const double* __restrict__ Qd, const double* __restrict__ Kd,
    float* __restrict__ out)
{
  __shared__ float As[16][68];   // [k][q]
  __shared__ float Bs[16][68];   // [k][m]
  const int tid = threadIdx.x;
  const int tx = tid & 15, ty = tid >> 4;
  const int b  = blockIdx.z;
  const int q0 = blockIdx.y * 64;
  const int m0 = blockIdx.x * 64;
  const size_t rowbase = (size_t)b * N_;

  float acc[4][4];
#pragma unroll
  for (int i = 0; i < 4; i++)
#pragma unroll
    for (int j = 0; j < 4; j++) acc[i][j] = 0.f;

  for (int k0 = 0; k0 < DK_; k0 += 16) {
    const int mt = tid >> 4;   // 0..15
    const int kt = tid & 15;   // 0..15
#pragma unroll
    for (int p = 0; p < 4; p++) {
      const int m = mt + 16 * p;
      As[kt][m] = (float)Qd[(rowbase + q0 + m) * DK_ + k0 + kt];
      Bs[kt][m] = (float)Kd[(rowbase + m0 + m) * DK_ + k0 + kt];
    }
    __syncthreads();
#pragma unroll
    for (int kk = 0; kk < 16; kk++) {
      float a[4], bb[4];
#pragma unroll
      for (int i = 0; i < 4; i++) a[i] = As[kk][ty * 4 + i];
#pragma unroll
      for (int j = 0; j < 4; j++) bb[j] = Bs[kk][tx * 4 + j];
#pragma unroll
      for (int i = 0; i < 4; i++)
#pragma unroll
        for (int j = 0; j < 4; j++)
          acc[i][j] = fmaf(a[i], bb[j], acc[i][j]);
    }
    __syncthreads();
  }

#pragma unroll
  for (int i = 0; i < 4; i++) {
    const size_t r = (size_t)b * N_ + q0 + ty * 4 + i;
#pragma unroll
    for (int j = 0; j < 4; j++)
      out[r * N_ + m0 + tx * 4 + j] = acc[i][j] * 0.0625f;
  }
}

// --------------------------------------------------------------------------
// Kernel 3: per-row exact top-32 (radix select + f64 rescore) and softmax.
// One block (256 threads) per row.
// --------------------------------------------------------------------------
__global__ __launch_bounds__(256) void topk_softmax_kernel(
    float* __restrict__ out, const double* __restrict__ Qd,
    const double* __restrict__ Kd)
{
  const int row = blockIdx.x;            // 0..16383
  const int b   = row >> 11;
  const int tid = threadIdx.x;
  float* rowp = out + (size_t)row * N_;

  __shared__ float    s[N_];             // 8 KB
  __shared__ double   qrow[DK_];         // 2 KB
  __shared__ unsigned hist[256];
  __shared__ unsigned sfx[256];
  __shared__ int      cidx[128];
  __shared__ double   cval[128];
  __shared__ float    ceval[128];
  __shared__ int      ncand_s;
  __shared__ unsigned prefix_s;
  __shared__ int      want_s;
  __shared__ double   vmax_s;
  __shared__ float    esum_s;

  for (int i = tid; i < N_; i += 256) s[i] = rowp[i];
  qrow[tid] = Qd[(size_t)row * DK_ + tid];   // DK_==256==blockDim
  __syncthreads();

  // ---- radix select: bits of the 32nd-largest value (descending) ----
  unsigned prefix = 0;
  int want = TOPK;
  for (int pass = 0; pass < 4; pass++) {
    hist[tid] = 0;
    __syncthreads();
    const int shift_b = 24 - 8 * pass;
    for (int i = tid; i < N_; i += 256) {
      unsigned u = __float_as_uint(s[i]);
      u = (u & 0x80000000u) ? ~u : (u | 0x80000000u);   // order-preserving
      const bool ok = (pass == 0) || ((u >> (shift_b + 8)) == prefix);
      if (ok) atomicAdd(&hist[(u >> shift_b) & 255u], 1u);
    }
    __syncthreads();
    // parallel suffix sum: sfx[d] = sum_{e>=d} hist[e]
    sfx[tid] = hist[tid];
    __syncthreads();
    for (int st = 1; st < 256; st <<= 1) {
      const unsigned add = (tid + st < 256) ? sfx[tid + st] : 0u;
      __syncthreads();
      sfx[tid] += add;
      __syncthreads();
    }
    const int gt = (int)(sfx[tid] - hist[tid]);   // count strictly above bucket tid
    if (gt < want && (int)sfx[tid] >= want) {
      prefix_s = (prefix << 8) | (unsigned)tid;
      want_s = want - gt;
    }
    __syncthreads();
    prefix = prefix_s;
    want = want_s;
    __syncthreads();
  }
  const unsigned su = prefix;
  const unsigned uu = (su & 0x80000000u) ? (su ^ 0x80000000u) : ~su;
  const float t32 = __uint_as_float(uu);
  const float cthr = t32 - 2e-4f;   // margin >> f32 GEMM error, << typical gap

  // ---- gather candidates ----
  if (tid == 0) ncand_s = 0;
  __syncthreads();
  for (int i = tid; i < N_; i += 256) {
    if (s[i] >= cthr) {
      const int p = atomicAdd(&ncand_s, 1);
      if (p < 128) cidx[p] = i;
    }
  }
  __syncthreads();
  int nc = ncand_s;
  if (nc > 128) nc = 128;

  // ---- f64 rescore of candidates (one wave per candidate) ----
  const int wid = tid >> 6, lane = tid & 63;
  for (int base = 0; base < nc; base += 4) {
    const int c = base + wid;
    if (c < nc) {
      const double* kp = Kd + ((size_t)b * N_ + cidx[c]) * DK_;
      double a = 0.0;
#pragma unroll
      for (int q = 0; q < 4; q++)
        a = fma(qrow[lane * 4 + q], kp[lane * 4 + q], a);
#pragma unroll
      for (int off = 32; off > 0; off >>= 1) a += __shfl_xor(a, off);
      if (lane == 0) cval[c] = a * 0.0625;
    }
  }
  __syncthreads();

  // ---- exact top-32 among candidates (jax tie-break: value desc, idx asc) --
  bool sel = false;
  double v = 0.0;
  int myidx = 0;
  if (tid < nc) {
    v = cval[tid];
    myidx = cidx[tid];
    int rank = 0;
    for (int j = 0; j < nc; j++) {
      const double vj = cval[j];
      rank += (vj > v) || (vj == v && cidx[j] < myidx);
    }
    sel = (rank < TOPK);
  }
  if (tid == 0) {
    double mx = cval[0];
    for (int j = 1; j < nc; j++) mx = cval[j] > mx ? cval[j] : mx;
    vmax_s = mx;   // max over candidates == max over selected
  }
  __syncthreads();
  const float ev = sel ? expf((float)(v - vmax_s)) : 0.f;
  if (tid < 128) ceval[tid] = ev;
  __syncthreads();
  if (tid == 0) {
    float ssum = 0.f;
    for (int j = 0; j < nc; j++) ssum += ceval[j];
    esum_s = ssum;
  }
  __syncthreads();

  // ---- write row: zeros + 32 softmax weights ----
  for (int i = tid; i < N_; i += 256) s[i] = 0.f;
  __syncthreads();
  if (tid < nc && sel) s[myidx] = ev / esum_s;
  __syncthreads();
  for (int i = tid; i < N_; i += 256) rowp[i] = s[i];
}

// --------------------------------------------------------------------------
extern "C" void kernel_launch(void* const* d_in, const int* in_sizes, int n_in,
                              void* d_out, int out_size, void* d_ws,
                              size_t ws_size, hipStream_t stream)
{
  const float* X  = (const float*)d_in[0];
  const float* Wq = (const float*)d_in[1];
  const float* bq = (const float*)d_in[2];
  const float* Wk = (const float*)d_in[3];
  const float* bk = (const float*)d_in[4];
  float* out = (float*)d_out;

  const size_t qk_elems = (size_t)M_ * DK_;
  if (ws_size < qk_elems * sizeof(double) * 2) return;  // need 67.1 MB
  double* Qd = (double*)d_ws;
  double* Kd = Qd + qk_elems;

  dim3 blk(256);
  dim3 g1(8, 256);          // 512/64 col tiles, 16384/64 row tiles
  proj_kernel<<<g1, blk, 0, stream>>>(X, Wq, bq, Wk, bk, Qd, Kd);

  dim3 g2(N_ / 64, N_ / 64, B_);   // 32 x 32 x 8
  score_kernel<<<g2, blk, 0, stream>>>(Qd, Kd, out);

  topk_softmax_kernel<<<dim3(M_), blk, 0, stream>>>(out, Qd, Kd);
}

// Round 2
// 676.641 us; speedup vs baseline: 1.2829x; 1.2829x over previous
//
#include <hip/hip_runtime.h>
#include <cstdint>
#include <cstddef>

#define B_   8
#define N_   2048
#define D_   1024
#define DK_  256
#define M_   (B_ * N_)   // 16384
#define TOPK 32

typedef unsigned short ushort_t;
typedef float  fvec4 __attribute__((ext_vector_type(4)));
typedef short  bvec8 __attribute__((ext_vector_type(8)));   // 8 bf16 (bits in shorts)
typedef float  avec4 __attribute__((ext_vector_type(4)));   // MFMA accumulator
typedef int    ivec4 __attribute__((ext_vector_type(4)));   // 16B staging

__device__ inline ushort_t f32_to_bf16_rn(float f) {
  unsigned u = __float_as_uint(f);
  u += 0x7fffu + ((u >> 16) & 1u);     // round-to-nearest-even (no inf/nan here)
  return (ushort_t)(u >> 16);
}

// --------------------------------------------------------------------------
// Kernel 1: fused Q/K projection GEMM, f64 accumulation.
// Tile 64(m) x 128(j), BK=16, per-thread 4x8. Also emits bf16 Q/K if ptrs set.
// --------------------------------------------------------------------------
__global__ __launch_bounds__(256) void proj_kernel(
    const float* __restrict__ X, const float* __restrict__ Wq,
    const float* __restrict__ bq, const float* __restrict__ Wk,
    const float* __restrict__ bk, double* __restrict__ Qd,
    double* __restrict__ Kd, ushort_t* __restrict__ Qbf,
    ushort_t* __restrict__ Kbf)
{
  __shared__ float As[16][68];    // [k][m]
  __shared__ float Bs[16][136];   // [k][j]
  const int tid = threadIdx.x;
  const int tx = tid & 15;        // 16 col-groups of 8
  const int ty = tid >> 4;        // 16 row-groups of 4
  const int m0 = blockIdx.y * 64;
  const int j0 = blockIdx.x * 128;         // 0,128,256,384
  const bool isQ = (j0 < 256);
  const float* Wp = isQ ? Wq : Wk;
  const float* bp = isQ ? bq : bk;
  const int jw = isQ ? j0 : (j0 - 256);

  double acc[4][8];
#pragma unroll
  for (int i = 0; i < 4; i++)
#pragma unroll
    for (int j = 0; j < 8; j++) acc[i][j] = 0.0;

  for (int k0 = 0; k0 < D_; k0 += 16) {
    {  // A tile: 64 rows x 16 k, transposed As[k][m]
      const int kt = tid & 15, mt = tid >> 4;
#pragma unroll
      for (int p = 0; p < 4; p++) {
        const int m = mt + 16 * p;
        As[kt][m] = X[(size_t)(m0 + m) * D_ + k0 + kt];
      }
    }
    {  // B tile: 16 k x 128 j (float4 loads/stores)
      const int c4 = tid & 31, kt = tid >> 5;
#pragma unroll
      for (int p = 0; p < 2; p++) {
        const int k = kt + 8 * p;
        fvec4 v = *(const fvec4*)&Wp[(size_t)(k0 + k) * DK_ + jw + c4 * 4];
        *(fvec4*)&Bs[k][c4 * 4] = v;
      }
    }
    __syncthreads();
#pragma unroll
    for (int kk = 0; kk < 16; kk++) {
      const fvec4 af  = *(const fvec4*)&As[kk][ty * 4];
      const fvec4 bf0 = *(const fvec4*)&Bs[kk][tx * 8];
      const fvec4 bf1 = *(const fvec4*)&Bs[kk][tx * 8 + 4];
      double a[4], b[8];
#pragma unroll
      for (int i = 0; i < 4; i++) a[i] = (double)af[i];
#pragma unroll
      for (int j = 0; j < 4; j++) { b[j] = (double)bf0[j]; b[j + 4] = (double)bf1[j]; }
#pragma unroll
      for (int i = 0; i < 4; i++)
#pragma unroll
        for (int j = 0; j < 8; j++)
          acc[i][j] = fma(a[i], b[j], acc[i][j]);
    }
    __syncthreads();
  }

#pragma unroll
  for (int i = 0; i < 4; i++) {
    const int m = m0 + ty * 4 + i;
#pragma unroll
    for (int j = 0; j < 8; j++) {
      const int c = jw + tx * 8 + j;
      const double v = acc[i][j] + (double)bp[c];
      const size_t off = (size_t)m * DK_ + c;
      if (isQ) {
        Qd[off] = v;
        if (Qbf) Qbf[off] = f32_to_bf16_rn((float)v);
      } else {
        Kd[off] = v;
        if (Kbf) Kbf[off] = f32_to_bf16_rn((float)v);
      }
    }
  }
}

// --------------------------------------------------------------------------
// Kernel 2a: scores via bf16 MFMA 16x16x32. Tile 128x128, 4 waves,
// per-wave 64x64 (4x4 fragments). Candidate-precision only.
// --------------------------------------------------------------------------
__global__ __launch_bounds__(256) void score_bf16_kernel(
    const ushort_t* __restrict__ Qb, const ushort_t* __restrict__ Kb,
    float* __restrict__ out)
{
  __shared__ ushort_t Asl[128 * 40];   // rows padded to 40 bf16 (80B)
  __shared__ ushort_t Bsl[128 * 40];
  const int tid = threadIdx.x;
  const int b  = blockIdx.z;
  const int q0 = blockIdx.y * 128;
  const int m0 = blockIdx.x * 128;
  const int w = tid >> 6, lane = tid & 63;
  const int wq = (w >> 1) * 64, wm = (w & 1) * 64;
  const int rsel = lane & 15, ksel = (lane >> 4) * 8;

  avec4 acc[4][4];
#pragma unroll
  for (int i = 0; i < 4; i++)
#pragma unroll
    for (int j = 0; j < 4; j++) acc[i][j] = (avec4)(0.f);

  for (int k0 = 0; k0 < DK_; k0 += 32) {
#pragma unroll
    for (int cc = 0; cc < 2; cc++) {   // 512 16B-chunks per array / 256 thr
      const int c = tid + cc * 256;
      const int r = c >> 2, part = c & 3;
      const ivec4 va = *(const ivec4*)&Qb[((size_t)b * N_ + q0 + r) * DK_ + k0 + part * 8];
      const ivec4 vb = *(const ivec4*)&Kb[((size_t)b * N_ + m0 + r) * DK_ + k0 + part * 8];
      *(ivec4*)&Asl[r * 40 + part * 8] = va;
      *(ivec4*)&Bsl[r * 40 + part * 8] = vb;
    }
    __syncthreads();
    bvec8 aF[4], bF[4];
#pragma unroll
    for (int mi = 0; mi < 4; mi++)
      aF[mi] = *(const bvec8*)&Asl[(wq + mi * 16 + rsel) * 40 + ksel];
#pragma unroll
    for (int nj = 0; nj < 4; nj++)
      bF[nj] = *(const bvec8*)&Bsl[(wm + nj * 16 + rsel) * 40 + ksel];
#pragma unroll
    for (int mi = 0; mi < 4; mi++)
#pragma unroll
      for (int nj = 0; nj < 4; nj++)
        acc[mi][nj] = __builtin_amdgcn_mfma_f32_16x16x32_bf16(
            aF[mi], bF[nj], acc[mi][nj], 0, 0, 0);
    __syncthreads();
  }

#pragma unroll
  for (int mi = 0; mi < 4; mi++)
#pragma unroll
    for (int nj = 0; nj < 4; nj++)
#pragma unroll
      for (int r = 0; r < 4; r++) {
        const int row = q0 + wq + mi * 16 + (lane >> 4) * 4 + r;
        const int col = m0 + wm + nj * 16 + (lane & 15);
        out[((size_t)b * N_ + row) * N_ + col] = acc[mi][nj][r] * 0.0625f;
      }
}

// --------------------------------------------------------------------------
// Kernel 2b (fallback if ws too small for bf16 copies): f32 scores from f64.
// --------------------------------------------------------------------------
__global__ __launch_bounds__(256) void score_f64_kernel(
    const double* __restrict__ Qd, const double* __restrict__ Kd,
    float* __restrict__ out)
{
  __shared__ float As[16][68];
  __shared__ float Bs[16][68];
  const int tid = threadIdx.x;
  const int tx = tid & 15, ty = tid >> 4;
  const int b  = blockIdx.z;
  const int q0 = blockIdx.y * 64;
  const int m0 = blockIdx.x * 64;
  const size_t rowbase = (size_t)b * N_;

  float acc[4][4];
#pragma unroll
  for (int i = 0; i < 4; i++)
#pragma unroll
    for (int j = 0; j < 4; j++) acc[i][j] = 0.f;

  for (int k0 = 0; k0 < DK_; k0 += 16) {
    const int mt = tid >> 4, kt = tid & 15;
#pragma unroll
    for (int p = 0; p < 4; p++) {
      const int m = mt + 16 * p;
      As[kt][m] = (float)Qd[(rowbase + q0 + m) * DK_ + k0 + kt];
      Bs[kt][m] = (float)Kd[(rowbase + m0 + m) * DK_ + k0 + kt];
    }
    __syncthreads();
#pragma unroll
    for (int kk = 0; kk < 16; kk++) {
      float a[4], bb[4];
#pragma unroll
      for (int i = 0; i < 4; i++) a[i] = As[kk][ty * 4 + i];
#pragma unroll
      for (int j = 0; j < 4; j++) bb[j] = Bs[kk][tx * 4 + j];
#pragma unroll
      for (int i = 0; i < 4; i++)
#pragma unroll
        for (int j = 0; j < 4; j++)
          acc[i][j] = fmaf(a[i], bb[j], acc[i][j]);
    }
    __syncthreads();
  }

#pragma unroll
  for (int i = 0; i < 4; i++) {
    const size_t r = (size_t)b * N_ + q0 + ty * 4 + i;
#pragma unroll
    for (int j = 0; j < 4; j++)
      out[r * N_ + m0 + tx * 4 + j] = acc[i][j] * 0.0625f;
  }
}

// --------------------------------------------------------------------------
// Kernel 3: per-row exact top-32 (radix select on noisy scores with margin,
// f64 rescore of candidates) and softmax. One block (256 threads) per row.
// --------------------------------------------------------------------------
__global__ __launch_bounds__(256) void topk_softmax_kernel(
    float* __restrict__ out, const double* __restrict__ Qd,
    const double* __restrict__ Kd, float margin)
{
  const int row = blockIdx.x;
  const int b   = row >> 11;
  const int tid = threadIdx.x;
  float* rowp = out + (size_t)row * N_;

  __shared__ float    s[N_];
  __shared__ double   qrow[DK_];
  __shared__ unsigned hist[256];
  __shared__ unsigned sfx[256];
  __shared__ int      cidx[128];
  __shared__ double   cval[128];
  __shared__ float    ceval[128];
  __shared__ int      ncand_s;
  __shared__ unsigned prefix_s;
  __shared__ int      want_s;
  __shared__ double   vmax_s;
  __shared__ float    esum_s;

  for (int i = tid; i < N_; i += 256) s[i] = rowp[i];
  qrow[tid] = Qd[(size_t)row * DK_ + tid];
  __syncthreads();

  // radix select: 32nd-largest noisy score
  unsigned prefix = 0;
  int want = TOPK;
  for (int pass = 0; pass < 4; pass++) {
    hist[tid] = 0;
    __syncthreads();
    const int shift_b = 24 - 8 * pass;
    for (int i = tid; i < N_; i += 256) {
      unsigned u = __float_as_uint(s[i]);
      u = (u & 0x80000000u) ? ~u : (u | 0x80000000u);
      const bool ok = (pass == 0) || ((u >> (shift_b + 8)) == prefix);
      if (ok) atomicAdd(&hist[(u >> shift_b) & 255u], 1u);
    }
    __syncthreads();
    sfx[tid] = hist[tid];
    __syncthreads();
    for (int st = 1; st < 256; st <<= 1) {
      const unsigned add = (tid + st < 256) ? sfx[tid + st] : 0u;
      __syncthreads();
      sfx[tid] += add;
      __syncthreads();
    }
    const int gt = (int)(sfx[tid] - hist[tid]);
    if (gt < want && (int)sfx[tid] >= want) {
      prefix_s = (prefix << 8) | (unsigned)tid;
      want_s = want - gt;
    }
    __syncthreads();
    prefix = prefix_s;
    want = want_s;
    __syncthreads();
  }
  const unsigned su = prefix;
  const unsigned uu = (su & 0x80000000u) ? (su ^ 0x80000000u) : ~su;
  const float t32 = __uint_as_float(uu);
  const float cthr = t32 - margin;

  // gather candidates
  if (tid == 0) ncand_s = 0;
  __syncthreads();
  for (int i = tid; i < N_; i += 256) {
    if (s[i] >= cthr) {
      const int p = atomicAdd(&ncand_s, 1);
      if (p < 128) cidx[p] = i;
    }
  }
  __syncthreads();
  int nc = ncand_s;
  if (nc > 128) nc = 128;

  // f64 rescore (one wave per candidate)
  const int wid = tid >> 6, lane = tid & 63;
  for (int base = 0; base < nc; base += 4) {
    const int c = base + wid;
    if (c < nc) {
      const double* kp = Kd + ((size_t)b * N_ + cidx[c]) * DK_;
      double a = 0.0;
#pragma unroll
      for (int q = 0; q < 4; q++)
        a = fma(qrow[lane * 4 + q], kp[lane * 4 + q], a);
#pragma unroll
      for (int off = 32; off > 0; off >>= 1) a += __shfl_xor(a, off);
      if (lane == 0) cval[c] = a * 0.0625;
    }
  }
  __syncthreads();

  // exact top-32 among candidates (value desc, index asc)
  bool sel = false;
  double v = 0.0;
  int myidx = 0;
  if (tid < nc) {
    v = cval[tid];
    myidx = cidx[tid];
    int rank = 0;
    for (int j = 0; j < nc; j++) {
      const double vj = cval[j];
      rank += (vj > v) || (vj == v && cidx[j] < myidx);
    }
    sel = (rank < TOPK);
  }
  if (tid == 0) {
    double mx = cval[0];
    for (int j = 1; j < nc; j++) mx = cval[j] > mx ? cval[j] : mx;
    vmax_s = mx;
  }
  __syncthreads();
  const float ev = sel ? expf((float)(v - vmax_s)) : 0.f;
  if (tid < 128) ceval[tid] = ev;
  __syncthreads();
  if (tid == 0) {
    float ssum = 0.f;
    for (int j = 0; j < nc; j++) ssum += ceval[j];
    esum_s = ssum;
  }
  __syncthreads();

  for (int i = tid; i < N_; i += 256) s[i] = 0.f;
  __syncthreads();
  if (tid < nc && sel) s[myidx] = ev / esum_s;
  __syncthreads();
  for (int i = tid; i < N_; i += 256) rowp[i] = s[i];
}

// --------------------------------------------------------------------------
extern "C" void kernel_launch(void* const* d_in, const int* in_sizes, int n_in,
                              void* d_out, int out_size, void* d_ws,
                              size_t ws_size, hipStream_t stream)
{
  const float* X  = (const float*)d_in[0];
  const float* Wq = (const float*)d_in[1];
  const float* bq = (const float*)d_in[2];
  const float* Wk = (const float*)d_in[3];
  const float* bk = (const float*)d_in[4];
  float* out = (float*)d_out;

  const size_t qk = (size_t)M_ * DK_;
  const size_t f64_bytes = qk * sizeof(double) * 2;           // 67.1 MB
  const size_t bf_bytes  = qk * sizeof(ushort_t) * 2;         // 16.8 MB
  if (ws_size < f64_bytes) return;
  const bool bfpath = (ws_size >= f64_bytes + bf_bytes);

  double* Qd = (double*)d_ws;
  double* Kd = Qd + qk;
  ushort_t* Qbf = (ushort_t*)(Kd + qk);
  ushort_t* Kbf = Qbf + qk;

  dim3 blk(256);
  proj_kernel<<<dim3(4, 256), blk, 0, stream>>>(
      X, Wq, bq, Wk, bk, Qd, Kd, bfpath ? Qbf : (ushort_t*)nullptr,
      bfpath ? Kbf : (ushort_t*)nullptr);

  float margin;
  if (bfpath) {
    score_bf16_kernel<<<dim3(N_ / 128, N_ / 128, B_), blk, 0, stream>>>(Qbf, Kbf, out);
    margin = 8e-3f;
  } else {
    score_f64_kernel<<<dim3(N_ / 64, N_ / 64, B_), blk, 0, stream>>>(Qd, Kd, out);
    margin = 2.5e-4f;
  }

  topk_softmax_kernel<<<dim3(M_), blk, 0, stream>>>(out, Qd, Kd, margin);
}